// Round 5
// baseline (151.423 us; speedup 1.0000x reference)
//
#include <hip/hip_runtime.h>

// TFMBSLinear forward on MI355X:
//   out[b][o] = sum_k sign(x[b][k]) * sign(w[o][k]) + bias[o]
// R4: LDS-FREE MXFP4 GEMM. The operand-order workspace layout (R3) means each
// lane's MFMA fragment sits at base + lane*16 in global memory -- a perfectly
// coalesced global_load_dwordx4. So: no LDS, no __syncthreads, no vmcnt(0)
// drains. B (2 MB) is L2-resident, A (8 MB) LLC-resident; compiler freely
// software-pipelines the barrier-less K-loop. C stores are nontemporal to
// keep A/B cached. Math exact (fp4 {0,+-1}, fp32 accum, sums <= 2048).

typedef int   intx4    __attribute__((ext_vector_type(4)));
typedef int   intx8    __attribute__((ext_vector_type(8)));
typedef float floatx16 __attribute__((ext_vector_type(16)));

static constexpr int M = 8192;   // batch
static constexpr int N = 2048;   // out features
static constexpr int K = 2048;   // in features
static constexpr int KB = K / 2; // 1024 packed bytes per row
static constexpr int BM = 128, BN = 128;

// Tiled layout (R3, verified): chunk g = s*2048 + c*64 + h*32 + r (16B chunks)
//   s = row strip (32 rows), c = kstep (64 elements = 32B/row), h = k-half,
//   r = row in strip; lane l = h*32 + r. Per (s,c): 1KB = one wave fragment.

// ---------------- quantize: fp32 -> sign fp4, tiled operand order ----------
__device__ __forceinline__ unsigned nib(float v) {
    // +1.0 -> 0x2, -1.0 -> 0xA, 0 -> 0x0 (e2m1)
    unsigned u = __float_as_uint(v);
    return (v != 0.0f) ? (0x2u | ((u >> 28) & 0x8u)) : 0u;
}

__device__ __forceinline__ unsigned pack8(const float4& a, const float4& b) {
    return  nib(a.x)        | (nib(a.y) << 4)  | (nib(a.z) << 8)  | (nib(a.w) << 12)
         | (nib(b.x) << 16) | (nib(b.y) << 20) | (nib(b.z) << 24) | (nib(b.w) << 28);
}

__global__ __launch_bounds__(256) void quant_tile(
    const float* __restrict__ x, const float* __restrict__ w,
    uint4* __restrict__ qx, uint4* __restrict__ qw, int nx, int ntot)
{
    int g = blockIdx.x * 256 + threadIdx.x;
    if (g >= ntot) return;
    const float* src; uint4* dst; int gg;
    if (g < nx) { gg = g; src = x; dst = qx; }
    else        { gg = g - nx; src = w; dst = qw; }
    const int r = gg & 31, h = (gg >> 5) & 1, c = (gg >> 6) & 31, s = gg >> 11;
    const int m = s * 32 + r;
    const float4* p = (const float4*)(src + (size_t)m * K + (c * 2 + h) * 32);
    uint4 o;
    o.x = pack8(p[0], p[1]);
    o.y = pack8(p[2], p[3]);
    o.z = pack8(p[4], p[5]);
    o.w = pack8(p[6], p[7]);
    dst[gg] = o;   // coalesced: consecutive threads -> consecutive 16B
}

// ---------------- LDS-free MXFP4 ternary GEMM, C = A * B^T + bias ----------
// 256 threads = 4 waves 2x2 over a 128x128 block tile; each wave: 64x64 as
// 2x2 accs of 32x32x64. K-loop: 32 ksteps, no barriers, direct global loads.
__device__ __forceinline__ intx8 ext4(intx4 v) {
    return __builtin_shufflevector(v, v, 0, 1, 2, 3, -1, -1, -1, -1);
}

__global__ __launch_bounds__(256, 4) void tgemm_fp4(
    const char* __restrict__ A,
    const char* __restrict__ B,
    const float* __restrict__ bias,
    float* __restrict__ C)
{
    const int tid  = threadIdx.x;
    const int wave = tid >> 6;
    const int lane = tid & 63;
    const int l32  = lane & 31;
    const int half = lane >> 5;

    const int bn = blockIdx.x * BN;   // n fast: blocks sharing A dispatch together
    const int bm = blockIdx.y * BM;

    const int wm = (wave & 1) * 64;
    const int wn = (wave >> 1) * 64;

    // Fragment base: strip stride 32768 B (32 ksteps x 1KB), kstep stride 1024.
    const char* pa = A + (size_t)((bm + wm) >> 5) * 32768 + lane * 16;
    const char* pb = B + (size_t)((bn + wn) >> 5) * 32768 + lane * 16;

    floatx16 acc[2][2] = {};

    #pragma unroll 4
    for (int c = 0; c < 32; ++c) {
        intx4 a0 = *reinterpret_cast<const intx4*>(pa + c * 1024);
        intx4 a1 = *reinterpret_cast<const intx4*>(pa + 32768 + c * 1024);
        intx4 b0 = *reinterpret_cast<const intx4*>(pb + c * 1024);
        intx4 b1 = *reinterpret_cast<const intx4*>(pb + 32768 + c * 1024);
        // cbsz=4 (A=FP4), blgp=4 (B=FP4); scale 127 = 2^0 = 1.0
        acc[0][0] = __builtin_amdgcn_mfma_scale_f32_32x32x64_f8f6f4(
            ext4(a0), ext4(b0), acc[0][0], 4, 4, 0, 127, 0, 127);
        acc[0][1] = __builtin_amdgcn_mfma_scale_f32_32x32x64_f8f6f4(
            ext4(a0), ext4(b1), acc[0][1], 4, 4, 0, 127, 0, 127);
        acc[1][0] = __builtin_amdgcn_mfma_scale_f32_32x32x64_f8f6f4(
            ext4(a1), ext4(b0), acc[1][0], 4, 4, 0, 127, 0, 127);
        acc[1][1] = __builtin_amdgcn_mfma_scale_f32_32x32x64_f8f6f4(
            ext4(a1), ext4(b1), acc[1][1], 4, 4, 0, 127, 0, 127);
    }

    // Epilogue: 32x32 C/D: col = lane&31, row = (reg&3)+8*(reg>>2)+4*half
    const int cn0 = bn + wn + l32;
    const float bc0 = bias[cn0];
    const float bc1 = bias[cn0 + 32];
    const int rbase = bm + wm + 4 * half;

    #pragma unroll
    for (int i = 0; i < 2; ++i) {
        #pragma unroll
        for (int r = 0; r < 16; ++r) {
            const int row = rbase + 32 * i + (r & 3) + 8 * (r >> 2);
            __builtin_nontemporal_store(acc[i][0][r] + bc0,
                                        &C[(size_t)row * N + cn0]);
            __builtin_nontemporal_store(acc[i][1][r] + bc1,
                                        &C[(size_t)row * N + cn0 + 32]);
        }
    }
}

extern "C" void kernel_launch(void* const* d_in, const int* in_sizes, int n_in,
                              void* d_out, int out_size, void* d_ws, size_t ws_size,
                              hipStream_t stream) {
    const float* x    = (const float*)d_in[0];   // [M,K] fp32
    const float* w    = (const float*)d_in[1];   // [N,K] fp32
    const float* bias = (const float*)d_in[2];   // [N]   fp32
    float* out = (float*)d_out;                  // [M,N] fp32

    // workspace: qx (8 MB) then qw (2 MB), operand-tiled packed fp4
    char* qx = (char*)d_ws;
    char* qw = qx + (size_t)M * KB;

    const int nx   = (M * KB) / 16;              // 524,288 chunks
    const int ntot = nx + (N * KB) / 16;         // 655,360
    quant_tile<<<ntot / 256, 256, 0, stream>>>(
        x, w, (uint4*)qx, (uint4*)qw, nx, ntot);

    dim3 grid(N / BN, M / BM);   // 16 x 64, n fast
    tgemm_fp4<<<grid, 256, 0, stream>>>(qx, qw, bias, out);
}